// Round 1
// baseline (113.974 us; speedup 1.0000x reference)
//
#include <hip/hip_runtime.h>

// Problem shape (fixed): N=4096 rows, D=128 in-dim, P=128 pe-dim, H=256 hidden.
// out: (N, D+1) fp32, col 0 = ones, col j+1 = x[:,j] * (1 + g_j)
//
// Algebraic restructure:
//   base[n][h] = sum_i x[n][i]*W1[i][h] + b1[h]          (kernel 1, -> d_ws)
//   t = base[n][h] + W1[128+j][h] - x[n][j]*W1[j][h]
//   g = sum_h relu(t) * W2[h] + b2
//   out[n][1+j] = x[n][j] * (1 + g)

#define NROWS 4096
#define DIN   128
#define HDIM  256

// ---------------- Kernel 1: base = x @ W1[:128] + b1 ----------------
// block: 256 threads, 16 rows x 256 cols per block.
// thread: 2 cols (c0 = 2*(tid&127)), 8 rows (r0 = 8*(tid>>7)).
__global__ __launch_bounds__(256) void nimo_base(
    const float* __restrict__ x, const float* __restrict__ W1,
    const float* __restrict__ b1, float* __restrict__ baseb)
{
    __shared__ float xs[128 * 20 + 8];  // xT[i][r], row stride 20 (16B-aligned, conflict-light)
    const int tid = threadIdx.x;
    const int rowBase = blockIdx.x * 16;

    // Stage x tile transposed: xs[i*20 + r] = x[rowBase+r][i] (coalesced global reads)
    #pragma unroll
    for (int t = 0; t < 8; ++t) {
        const int idx = t * 256 + tid;
        const int r = idx >> 7;      // 0..15
        const int i = idx & 127;
        xs[i * 20 + r] = x[(rowBase + r) * DIN + i];
    }
    __syncthreads();

    const int c0 = (tid & 127) * 2;
    const int r0 = (tid >> 7) * 8;

    float acc[8][2];
    #pragma unroll
    for (int k = 0; k < 8; ++k) { acc[k][0] = 0.f; acc[k][1] = 0.f; }

    for (int i = 0; i < DIN; ++i) {
        const float2 w  = *(const float2*)(W1 + i * HDIM + c0);   // coalesced, L2-hot
        const float4 xa = *(const float4*)(&xs[i * 20 + r0]);     // broadcast LDS
        const float4 xb = *(const float4*)(&xs[i * 20 + r0 + 4]);
        acc[0][0] = fmaf(xa.x, w.x, acc[0][0]); acc[0][1] = fmaf(xa.x, w.y, acc[0][1]);
        acc[1][0] = fmaf(xa.y, w.x, acc[1][0]); acc[1][1] = fmaf(xa.y, w.y, acc[1][1]);
        acc[2][0] = fmaf(xa.z, w.x, acc[2][0]); acc[2][1] = fmaf(xa.z, w.y, acc[2][1]);
        acc[3][0] = fmaf(xa.w, w.x, acc[3][0]); acc[3][1] = fmaf(xa.w, w.y, acc[3][1]);
        acc[4][0] = fmaf(xb.x, w.x, acc[4][0]); acc[4][1] = fmaf(xb.x, w.y, acc[4][1]);
        acc[5][0] = fmaf(xb.y, w.x, acc[5][0]); acc[5][1] = fmaf(xb.y, w.y, acc[5][1]);
        acc[6][0] = fmaf(xb.z, w.x, acc[6][0]); acc[6][1] = fmaf(xb.z, w.y, acc[6][1]);
        acc[7][0] = fmaf(xb.w, w.x, acc[7][0]); acc[7][1] = fmaf(xb.w, w.y, acc[7][1]);
    }

    const float2 bb = *(const float2*)(b1 + c0);
    #pragma unroll
    for (int k = 0; k < 8; ++k) {
        float2 v; v.x = acc[k][0] + bb.x; v.y = acc[k][1] + bb.y;
        *(float2*)(baseb + (size_t)(rowBase + r0 + k) * HDIM + c0) = v;
    }
}

// ---------------- Kernel 2: masked-MLP evaluation ----------------
// block: 256 threads = 4 waves; wave handles 8 rows; lane = (r = lane&7, c = lane>>3).
// Each lane owns h-chunk c*32..c*32+31 (base + W2 chunks preloaded in registers).
// Loop over 32 j's; 3x shfl_xor reduction across the 8 c-lanes; no barriers.
__global__ __launch_bounds__(256) void nimo_main(
    const float* __restrict__ x, const float* __restrict__ W1,
    const float* __restrict__ W2, const float* __restrict__ b2,
    const float* __restrict__ baseb, float* __restrict__ out)
{
    const int lane = threadIdx.x & 63;
    const int wave = threadIdx.x >> 6;
    const int r = lane & 7;
    const int c = lane >> 3;
    const int row = blockIdx.x * 32 + wave * 8 + r;
    const int j0 = blockIdx.y * 32;

    float4 bb[8], w2v[8];
    const float4* bbp = (const float4*)(baseb + (size_t)row * HDIM + c * 32);
    const float4* w2p = (const float4*)(W2 + c * 32);
    #pragma unroll
    for (int k = 0; k < 8; ++k) { bb[k] = bbp[k]; w2v[k] = w2p[k]; }
    const float b2s = b2[0];

    if (blockIdx.y == 0 && c == 0) out[(size_t)row * 129] = 1.0f;

    for (int j = j0; j < j0 + 32; ++j) {
        const float xj = x[(size_t)row * DIN + j];
        const float4* wap = (const float4*)(W1 + (size_t)j * HDIM + c * 32);
        const float4* wpp = (const float4*)(W1 + (size_t)(DIN + j) * HDIM + c * 32);
        float acc = 0.f;
        #pragma unroll
        for (int k = 0; k < 8; ++k) {
            const float4 wa = wap[k];
            const float4 wp = wpp[k];
            float t;
            t = fmaf(-xj, wa.x, bb[k].x + wp.x); t = fmaxf(t, 0.f); acc = fmaf(t, w2v[k].x, acc);
            t = fmaf(-xj, wa.y, bb[k].y + wp.y); t = fmaxf(t, 0.f); acc = fmaf(t, w2v[k].y, acc);
            t = fmaf(-xj, wa.z, bb[k].z + wp.z); t = fmaxf(t, 0.f); acc = fmaf(t, w2v[k].z, acc);
            t = fmaf(-xj, wa.w, bb[k].w + wp.w); t = fmaxf(t, 0.f); acc = fmaf(t, w2v[k].w, acc);
        }
        acc += __shfl_xor(acc, 8);
        acc += __shfl_xor(acc, 16);
        acc += __shfl_xor(acc, 32);
        if (c == 0) out[(size_t)row * 129 + 1 + j] = xj * (1.0f + acc + b2s);
    }
}

extern "C" void kernel_launch(void* const* d_in, const int* in_sizes, int n_in,
                              void* d_out, int out_size, void* d_ws, size_t ws_size,
                              hipStream_t stream) {
    const float* x  = (const float*)d_in[0];   // 4096*128
    const float* W1 = (const float*)d_in[1];   // 256*256
    const float* b1 = (const float*)d_in[2];   // 256
    const float* W2 = (const float*)d_in[3];   // 256
    const float* b2 = (const float*)d_in[4];   // 1
    float* out = (float*)d_out;                // 4096*129
    float* baseb = (float*)d_ws;               // 4096*256 fp32 = 4 MB scratch

    nimo_base<<<dim3(NROWS / 16), 256, 0, stream>>>(x, W1, b1, baseb);
    nimo_main<<<dim3(NROWS / 32, DIN / 32), 256, 0, stream>>>(x, W1, W2, b2, baseb, out);
}

// Round 2
// 113.304 us; speedup vs baseline: 1.0059x; 1.0059x over previous
//
#include <hip/hip_runtime.h>

// N=4096 rows, D=128 in-dim, P=128 pe-dim, H=256 hidden.
// out: (N, 129) fp32, col 0 = ones, col j+1 = x[:,j] * (1 + g_j)
//
//   base[n][h] = sum_i x[n][i]*W1[i][h] + b1[h]          (kernel 1 -> d_ws)
//   g = sum_h relu(base[n][h] + W1[128+j][h] - x[n][j]*W1[j][h]) * W2[h] + b2
//   out[n][1+j] = x[n][j] * (1 + g)

#define NROWS 4096
#define DIN   128
#define HDIM  256

// ---------------- Kernel 1: base = x @ W1[:128] + b1 ----------------
// 512 blocks (8 rows each), 256 threads; thread = 1 col x 8 rows.
// x reads are block-uniform -> scalar loads; i-unroll 8 keeps 8 W1 loads in flight.
__global__ __launch_bounds__(256) void nimo_base(
    const float* __restrict__ x, const float* __restrict__ W1,
    const float* __restrict__ b1, float* __restrict__ baseb)
{
    const int col  = threadIdx.x;          // 0..255
    const int row0 = blockIdx.x * 8;
    const float* __restrict__ xr = x + (size_t)row0 * DIN;

    float acc[8];
    #pragma unroll
    for (int r = 0; r < 8; ++r) acc[r] = 0.f;

    #pragma unroll 8
    for (int i = 0; i < DIN; ++i) {
        const float w = W1[i * HDIM + col];   // coalesced vector load, L2-hot
        #pragma unroll
        for (int r = 0; r < 8; ++r)
            acc[r] = fmaf(xr[r * DIN + i], w, acc[r]);   // xr[...] uniform -> s_load
    }

    const float bv = b1[col];
    #pragma unroll
    for (int r = 0; r < 8; ++r)
        baseb[(size_t)(row0 + r) * HDIM + col] = acc[r] + bv;
}

// ---------------- Kernel 2: masked-MLP evaluation ----------------
// Grid: (4096/16) x (128/32) = 1024 blocks, 256 threads = 4 waves.
// Wave: 4 rows (r=lane&3) x 16 h-chunks of 16 (c=lane>>2). Per-lane resident:
// base chunk (4xfloat4) + W2 chunk (4xfloat4). j-loop double-buffers the
// 8 W1 float4 loads for j+1 while computing j. Reduce over c via 4 shfl_xor.
__global__ __launch_bounds__(256, 4) void nimo_main(
    const float* __restrict__ x, const float* __restrict__ W1,
    const float* __restrict__ W2, const float* __restrict__ b2,
    const float* __restrict__ baseb, float* __restrict__ out)
{
    const int lane = threadIdx.x & 63;
    const int wave = threadIdx.x >> 6;
    const int r = lane & 3;
    const int c = lane >> 2;               // 0..15
    const int row = blockIdx.x * 16 + wave * 4 + r;
    const int j0 = blockIdx.y * 32;
    const int h0 = c * 16;

    float4 bb[4], w2v[4];
    const float4* bbp = (const float4*)(baseb + (size_t)row * HDIM + h0);
    const float4* w2p = (const float4*)(W2 + h0);
    #pragma unroll
    for (int k = 0; k < 4; ++k) { bb[k] = bbp[k]; w2v[k] = w2p[k]; }
    const float b2s = b2[0];

    if (blockIdx.y == 0 && c == 0) out[(size_t)row * 129] = 1.0f;

    const float* wa_base = W1 + (size_t)j0 * HDIM + h0;
    const float* wp_base = W1 + (size_t)(DIN + j0) * HDIM + h0;

    float4 wa[4], wp[4];
    #pragma unroll
    for (int k = 0; k < 4; ++k) {
        wa[k] = ((const float4*)wa_base)[k];
        wp[k] = ((const float4*)wp_base)[k];
    }

    #pragma unroll 2
    for (int jj = 0; jj < 32; ++jj) {
        const int j = j0 + jj;
        const float xj = x[(size_t)row * DIN + j];

        float4 na[4], np_[4];
        if (jj < 31) {
            const float4* nap = (const float4*)(wa_base + (jj + 1) * HDIM);
            const float4* npp = (const float4*)(wp_base + (jj + 1) * HDIM);
            #pragma unroll
            for (int k = 0; k < 4; ++k) { na[k] = nap[k]; np_[k] = npp[k]; }
        }

        float acc = 0.f;
        #pragma unroll
        for (int k = 0; k < 4; ++k) {
            float t;
            t = fmaf(-xj, wa[k].x, bb[k].x + wp[k].x); t = fmaxf(t, 0.f); acc = fmaf(t, w2v[k].x, acc);
            t = fmaf(-xj, wa[k].y, bb[k].y + wp[k].y); t = fmaxf(t, 0.f); acc = fmaf(t, w2v[k].y, acc);
            t = fmaf(-xj, wa[k].z, bb[k].z + wp[k].z); t = fmaxf(t, 0.f); acc = fmaf(t, w2v[k].z, acc);
            t = fmaf(-xj, wa[k].w, bb[k].w + wp[k].w); t = fmaxf(t, 0.f); acc = fmaf(t, w2v[k].w, acc);
        }
        acc += __shfl_xor(acc, 4);
        acc += __shfl_xor(acc, 8);
        acc += __shfl_xor(acc, 16);
        acc += __shfl_xor(acc, 32);
        if (c == 0) out[(size_t)row * 129 + 1 + j] = xj * (1.0f + acc + b2s);

        if (jj < 31) {
            #pragma unroll
            for (int k = 0; k < 4; ++k) { wa[k] = na[k]; wp[k] = np_[k]; }
        }
    }
}

extern "C" void kernel_launch(void* const* d_in, const int* in_sizes, int n_in,
                              void* d_out, int out_size, void* d_ws, size_t ws_size,
                              hipStream_t stream) {
    const float* x  = (const float*)d_in[0];   // 4096*128
    const float* W1 = (const float*)d_in[1];   // 256*256
    const float* b1 = (const float*)d_in[2];   // 256
    const float* W2 = (const float*)d_in[3];   // 256
    const float* b2 = (const float*)d_in[4];   // 1
    float* out = (float*)d_out;                // 4096*129
    float* baseb = (float*)d_ws;               // 4096*256 fp32 = 4 MB scratch

    nimo_base<<<dim3(NROWS / 8), 256, 0, stream>>>(x, W1, b1, baseb);
    nimo_main<<<dim3(NROWS / 16, DIN / 32), 256, 0, stream>>>(x, W1, W2, b2, baseb, out);
}

// Round 3
// 93.465 us; speedup vs baseline: 1.2194x; 1.2123x over previous
//
#include <hip/hip_runtime.h>

// N=4096 rows, D=128 in-dim, P=128 pe-dim, H=256 hidden.
// out: (N, 129) fp32, col 0 = ones, col j+1 = x[:,j] * (1 + g_j)
//
//   base[n][h] = sum_i x[n][i]*W1[i][h] + b1[h]          (kernel 1 -> d_ws)
//   g = sum_h relu(base[n][h] + W1[128+j][h] - x[n][j]*W1[j][h]) * W2[h] + b2
//   out[n][1+j] = x[n][j] * (1 + g)

#define NROWS 4096
#define DIN   128
#define HDIM  256
#define JCH   16

// ---------------- Kernel 1: base = x @ W1[:128] + b1 ----------------
// grid (128,4), block 256. Tile 32 rows x 64 h, full K=128 of x staged
// transposed in LDS (stride 36 keeps 16B alignment for ds_read_b128).
// Thread = 4 rows x 2 h; per k: 1 float2 W1 load + 1 ds_read_b128 + 8 fma.
__global__ __launch_bounds__(256) void nimo_base(
    const float* __restrict__ x, const float* __restrict__ W1,
    const float* __restrict__ b1, float* __restrict__ baseb)
{
    __shared__ float xs[DIN * 36];           // xs[k*36 + r]
    const int tid  = threadIdx.x;
    const int row0 = blockIdx.x * 32;
    const int h0   = blockIdx.y * 64;

    {   // stage x transposed: 16 floats per thread
        const int bidx = tid * 16;
        const int r = bidx >> 7;             // 0..31
        const int c = bidx & 127;
        #pragma unroll
        for (int u = 0; u < 4; ++u) {
            const float4 v = *(const float4*)(x + (size_t)(row0 + r) * DIN + c + u * 4);
            xs[(c + u * 4 + 0) * 36 + r] = v.x;
            xs[(c + u * 4 + 1) * 36 + r] = v.y;
            xs[(c + u * 4 + 2) * 36 + r] = v.z;
            xs[(c + u * 4 + 3) * 36 + r] = v.w;
        }
    }
    __syncthreads();

    const int tx = tid & 31;                 // h pair: h0 + tx*2
    const int ty = tid >> 5;                 // row quad: row0 + ty*4 ..
    const float* __restrict__ wcol = W1 + h0 + tx * 2;

    float2 acc[4];
    #pragma unroll
    for (int u = 0; u < 4; ++u) { acc[u].x = 0.f; acc[u].y = 0.f; }

    #pragma unroll 8
    for (int k = 0; k < DIN; ++k) {
        const float2 w  = *(const float2*)(wcol + (size_t)k * HDIM);
        const float4 xv = *(const float4*)(&xs[k * 36 + ty * 4]);
        acc[0].x = fmaf(xv.x, w.x, acc[0].x); acc[0].y = fmaf(xv.x, w.y, acc[0].y);
        acc[1].x = fmaf(xv.y, w.x, acc[1].x); acc[1].y = fmaf(xv.y, w.y, acc[1].y);
        acc[2].x = fmaf(xv.z, w.x, acc[2].x); acc[2].y = fmaf(xv.z, w.y, acc[2].y);
        acc[3].x = fmaf(xv.w, w.x, acc[3].x); acc[3].y = fmaf(xv.w, w.y, acc[3].y);
    }

    const float2 bv = *(const float2*)(b1 + h0 + tx * 2);
    #pragma unroll
    for (int u = 0; u < 4; ++u) {
        float2 o; o.x = acc[u].x + bv.x; o.y = acc[u].y + bv.y;
        *(float2*)(baseb + (size_t)(row0 + ty * 4 + u) * HDIM + h0 + tx * 2) = o;
    }
}

// ---------------- Kernel 2: masked-MLP evaluation ----------------
// grid (64, 8), block 512 = 8 waves. lane = row (r = tid&63), wave q owns
// h-chunk [q*32, q*32+32). Per lane register-resident: bb[32] (base chunk),
// w2r[32]. j is wave-uniform -> W1 rows via SCALAR loads (readfirstlane'd
// base address). Inner loop: pure VALU, 4 ops/h, no vector mem, no shfl.
// 8-way h-partials combined once at the end through LDS.
__global__ __launch_bounds__(512, 4) void nimo_main(
    const float* __restrict__ x, const float* __restrict__ W1,
    const float* __restrict__ W2, const float* __restrict__ b2,
    const float* __restrict__ baseb, float* __restrict__ out)
{
    __shared__ float part[8][JCH][64];       // 32 KB
    const int tid  = threadIdx.x;
    const int r    = tid & 63;
    const int q    = tid >> 6;               // wave id 0..7
    const int row0 = blockIdx.x * 64;
    const int row  = row0 + r;
    const int j0   = blockIdx.y * JCH;
    const int h0   = __builtin_amdgcn_readfirstlane(q * 32);

    float bb[32];
    {
        const float4* bp = (const float4*)(baseb + (size_t)row * HDIM + h0);
        #pragma unroll
        for (int u = 0; u < 8; ++u) ((float4*)bb)[u] = bp[u];
    }
    float w2r[32];
    {
        const float* __restrict__ w2p = W2 + h0;
        #pragma unroll
        for (int u = 0; u < 32; ++u) w2r[u] = w2p[u];
    }

    const float* __restrict__ xrow = x + (size_t)row * DIN;
    float nxj = xrow[j0];

    for (int jj = 0; jj < JCH; ++jj) {
        const float xj = nxj;
        if (jj + 1 < JCH) nxj = xrow[j0 + jj + 1];   // prefetch next xj
        const float* __restrict__ wa = W1 + (size_t)(j0 + jj) * HDIM + h0;  // uniform -> s_load
        const float* __restrict__ wp = wa + DIN * HDIM;
        float acc = 0.f;
        #pragma unroll
        for (int h = 0; h < 32; ++h) {
            float t = bb[h] + wp[h];          // v_add (sgpr src)
            t = fmaf(-xj, wa[h], t);          // v_fma (sgpr src)
            t = fmaxf(t, 0.f);                // v_max
            acc = fmaf(t, w2r[h], acc);       // v_fma
        }
        part[q][jj][r] = acc;                 // banks = r: conflict-free
    }
    __syncthreads();

    const float b2s = b2[0];
    if (blockIdx.y == 0 && tid < 64) out[(size_t)(row0 + tid) * 129] = 1.0f;

    #pragma unroll
    for (int e = 0; e < 2; ++e) {
        const int idx = e * 512 + tid;        // 1024 (row,j) results
        const int jj  = idx >> 6;
        const int rr  = idx & 63;
        float g = 0.f;
        #pragma unroll
        for (int qq = 0; qq < 8; ++qq) g += part[qq][jj][rr];
        const float xv = x[(size_t)(row0 + rr) * DIN + j0 + jj];
        out[(size_t)(row0 + rr) * 129 + 1 + j0 + jj] = xv * (1.0f + g + b2s);
    }
}

extern "C" void kernel_launch(void* const* d_in, const int* in_sizes, int n_in,
                              void* d_out, int out_size, void* d_ws, size_t ws_size,
                              hipStream_t stream) {
    const float* x  = (const float*)d_in[0];   // 4096*128
    const float* W1 = (const float*)d_in[1];   // 256*256
    const float* b1 = (const float*)d_in[2];   // 256
    const float* W2 = (const float*)d_in[3];   // 256
    const float* b2 = (const float*)d_in[4];   // 1
    float* out = (float*)d_out;                // 4096*129
    float* baseb = (float*)d_ws;               // 4096*256 fp32 = 4 MB scratch

    nimo_base<<<dim3(NROWS / 32, HDIM / 64), 256, 0, stream>>>(x, W1, b1, baseb);
    nimo_main<<<dim3(NROWS / 64, DIN / JCH), 512, 0, stream>>>(x, W1, W2, b2, baseb, out);
}